// Round 7
// baseline (125.153 us; speedup 1.0000x reference)
//
#include <hip/hip_runtime.h>
#include <hip/hip_bf16.h>

typedef __attribute__((ext_vector_type(8))) short bf16x8;
typedef __attribute__((ext_vector_type(16))) float f32x16;

#define U_LD 2176      // padded K (multiple of 64)
#define K_REAL 2145    // 33*65
#define NKT 34         // 2176/64
#define DIM0 33
#define DIM1 33
#define DIM2 65
#define NROW 2048
#define OO 128

__device__ __forceinline__ unsigned short f2bf(float f) {
  union { float f; unsigned u; } v; v.f = f;
  unsigned r = v.u + 0x7fffu + ((v.u >> 16) & 1u);   // round-to-nearest-even
  return (unsigned short)(r >> 16);
}

#define GLOAD_LDS16(SRC, DST) \
  __builtin_amdgcn_global_load_lds((const __attribute__((address_space(1))) void*)(SRC), \
                                   (__attribute__((address_space(3))) void*)(DST), 16, 0, 0)

// ---- U[n][k] = bf16( x1[n,b] * x2[n,c] ),  k = b*65+c, zero-padded to 2176 ----
__global__ __launch_bounds__(256) void prep_u_kernel(const float* __restrict__ x1,
                                                     const float* __restrict__ x2,
                                                     ushort* __restrict__ U) {
  __shared__ float s1[DIM1], s2[DIM2];
  int n = blockIdx.x;
  int tid = threadIdx.x;
  if (tid < DIM1) s1[tid] = x1[n * DIM1 + tid];
  int t2 = tid - DIM1;
  if (t2 >= 0 && t2 < DIM2) s2[t2] = x2[n * DIM2 + t2];
  __syncthreads();
  for (int k8 = tid; k8 < U_LD / 8; k8 += 256) {
    union { ushort us[8]; uint4 v; } pk;
#pragma unroll
    for (int j = 0; j < 8; ++j) {
      int k = k8 * 8 + j;
      float val = 0.f;
      if (k < K_REAL) { int b = k / DIM2; int c = k - b * DIM2; val = s1[b] * s2[c]; }
      pk.us[j] = f2bf(val);
    }
    *(uint4*)&U[(size_t)n * U_LD + k8 * 8] = pk.v;
  }
}

// ---- Wt[a][o][k] = bf16( W[a,b,c,o] ), k = b*65+c, zero-padded ----
__global__ __launch_bounds__(256) void prep_wt_kernel(const float* __restrict__ W,
                                                      ushort* __restrict__ Wt) {
  __shared__ ushort s[64][130];   // [k][o], pad to 130 to spread banks
  int a = blockIdx.y;
  int k0 = blockIdx.x * 64;       // 34 slabs of 64 k
  int tid = threadIdx.x;
  for (int idx = tid; idx < 64 * 32; idx += 256) {
    int kk = idx >> 5;
    int og = (idx & 31) * 4;
    int k = k0 + kk;
    float4 v = make_float4(0.f, 0.f, 0.f, 0.f);
    if (k < K_REAL) {
      int b = k / DIM2; int c = k - b * DIM2;
      v = *(const float4*)&W[(((size_t)a * DIM1 + b) * DIM2 + c) * OO + og];
    }
    s[kk][og]     = f2bf(v.x);
    s[kk][og + 1] = f2bf(v.y);
    s[kk][og + 2] = f2bf(v.z);
    s[kk][og + 3] = f2bf(v.w);
  }
  __syncthreads();
  int o  = tid >> 1;
  int kh = (tid & 1) * 32;
  union { ushort us[32]; uint4 v[4]; } pk;
#pragma unroll
  for (int j = 0; j < 32; ++j) pk.us[j] = s[kh + j][o];
  uint4* dst = (uint4*)&Wt[((size_t)a * OO + o) * U_LD + k0 + kh];
#pragma unroll
  for (int q = 0; q < 4; ++q) dst[q] = pk.v[q];
}

// ---- main GEMM: 128x128 tile, one a per block, 32x32x16 MFMA, 4 waves of
//      64x64. Counted-vmcnt double-buffer (R4 pipeline): s_barrier + vmcnt(8),
//      never drain to 0 in the main loop. ----
__global__ __launch_bounds__(256, 2) void gemm_kernel(const ushort* __restrict__ U,
                                                      const ushort* __restrict__ Wt,
                                                      const float* __restrict__ x0,
                                                      float* __restrict__ out) {
  // per buffer: A [128 rows][64 k] = 16KB (ushort 0..8191), B [128 o][64 k] = 16KB (8192..16383)
  __shared__ ushort lds[2][16384];   // 64 KB -> 2 blocks/CU

  int tid = threadIdx.x;
  int lane = tid & 63;
  int w = tid >> 6;
  int wr = w >> 1, wc = w & 1;       // wave tile: rows wr*64.., cols wc*64..

  // XCD-aware bijective swizzle: 528 blocks, 66 per XCD, a-major within XCD.
  int orig = (int)blockIdx.x;
  int logical = (orig & 7) * 66 + (orig >> 3);
  int a = logical / 16;        // 0..32
  int m = logical & 15;        // 0..15
  int n0 = m * 128;

  int r31 = lane & 31;
  int ghi = lane >> 5;         // granule bit from lane

  f32x16 acc[2][2];
#pragma unroll
  for (int mi = 0; mi < 2; ++mi)
#pragma unroll
    for (int ni = 0; ni < 2; ++ni)
      acc[mi][ni] = (f32x16){0.f,0.f,0.f,0.f,0.f,0.f,0.f,0.f,0.f,0.f,0.f,0.f,0.f,0.f,0.f,0.f};

  const ushort* WtA = Wt + (size_t)a * OO * U_LD;

  // --- per-thread staging: 8 chunks (4 A + 4 B), pointer-bumped +64 ushorts/step ---
  // chunk c in 0..1023: row = c>>3, slot = c&7; LDS dest linear c*16 bytes;
  // global source granule = slot ^ (row&7)  (involution, undone on read side)
  const ushort* pA[4]; const ushort* pB[4];
  int dA[4], dB[4];
#pragma unroll
  for (int i = 0; i < 4; ++i) {
    int c = i * 256 + tid;
    int row = c >> 3;
    int ss = (c & 7) ^ (row & 7);
    pA[i] = U + (size_t)(n0 + row) * U_LD + ss * 8;
    dA[i] = c * 8;
    pB[i] = WtA + (size_t)row * U_LD + ss * 8;
    dB[i] = 8192 + c * 8;
  }

  auto STAGE = [&](ushort* Lb) {
#pragma unroll
    for (int i = 0; i < 4; ++i) { GLOAD_LDS16(pA[i], Lb + dA[i]); pA[i] += 64; }
#pragma unroll
    for (int i = 0; i < 4; ++i) { GLOAD_LDS16(pB[i], Lb + dB[i]); pB[i] += 64; }
  };

  // A-frag (32x16): row = base + (lane&31), k-granule(16B) = ks*2 + (lane>>5)
  // read byte = row*128 + (granule ^ (row&7))*16  -> uniform bank spread
  auto COMPUTE = [&](const ushort* Lb) {
    const char* base = (const char*)Lb;
    bf16x8 af[2][4], bfr[2][4];
#pragma unroll
    for (int mi = 0; mi < 2; ++mi) {
      int row = wr * 64 + mi * 32 + r31;
      int rb = row * 128, rs = row & 7;
#pragma unroll
      for (int ks = 0; ks < 4; ++ks)
        af[mi][ks] = *(const bf16x8*)(base + rb + (((ks * 2 + ghi) ^ rs) << 4));
    }
#pragma unroll
    for (int ni = 0; ni < 2; ++ni) {
      int row = wc * 64 + ni * 32 + r31;
      int rb = 16384 + row * 128, rs = row & 7;
#pragma unroll
      for (int ks = 0; ks < 4; ++ks)
        bfr[ni][ks] = *(const bf16x8*)(base + rb + (((ks * 2 + ghi) ^ rs) << 4));
    }
    __builtin_amdgcn_s_setprio(1);
#pragma unroll
    for (int ks = 0; ks < 4; ++ks)
#pragma unroll
      for (int mi = 0; mi < 2; ++mi)
#pragma unroll
        for (int ni = 0; ni < 2; ++ni)
          acc[mi][ni] = __builtin_amdgcn_mfma_f32_32x32x16_bf16(af[mi][ks], bfr[ni][ks], acc[mi][ni], 0, 0, 0);
    __builtin_amdgcn_s_setprio(0);
  };

  // prologue: tiles 0,1 in flight (16 loads); wait tile 0 (16-8=8 oldest)
  STAGE(&lds[0][0]);
  STAGE(&lds[1][0]);
  asm volatile("s_waitcnt vmcnt(8)" ::: "memory");
  __builtin_amdgcn_s_barrier();

  // steady state: 2x unroll for compile-time buffer index.
  for (int it = 0; it < 16; ++it) {
    COMPUTE(&lds[0][0]);
    __builtin_amdgcn_s_barrier();            // readers done with b0
    STAGE(&lds[0][0]);                       // tile 2it+2 -> b0 (16 in flight)
    asm volatile("s_waitcnt vmcnt(8)" ::: "memory");   // b1's tile landed
    __builtin_amdgcn_s_barrier();
    COMPUTE(&lds[1][0]);
    __builtin_amdgcn_s_barrier();
    STAGE(&lds[1][0]);                       // tile 2it+3 -> b1
    asm volatile("s_waitcnt vmcnt(8)" ::: "memory");   // b0's tile landed
    __builtin_amdgcn_s_barrier();
  }
  // tiles 32 (b0, landed) and 33 (b1, in flight)
  COMPUTE(&lds[0][0]);
  asm volatile("s_waitcnt vmcnt(0)" ::: "memory");
  __builtin_amdgcn_s_barrier();
  COMPUTE(&lds[1][0]);

  // epilogue: C/D 32x32 layout: col = lane&31, row = (r&3) + 8*(r>>2) + 4*(lane>>5)
#pragma unroll
  for (int mi = 0; mi < 2; ++mi) {
#pragma unroll
    for (int r = 0; r < 16; ++r) {
      int row = n0 + wr * 64 + mi * 32 + (r & 3) + 8 * (r >> 2) + 4 * ghi;
      float s = x0[(size_t)row * DIM0 + a];
#pragma unroll
      for (int ni = 0; ni < 2; ++ni) {
        int col = wc * 64 + ni * 32 + r31;
        atomicAdd(&out[(size_t)row * OO + col], acc[mi][ni][r] * s);
      }
    }
  }
}

// ---- bias + relu, in place on d_out ----
__global__ __launch_bounds__(256) void relu_kernel(float* __restrict__ out,
                                                   const float* __restrict__ bias) {
  int i = blockIdx.x * 256 + threadIdx.x;
  out[i] = fmaxf(out[i] + bias[i & (OO - 1)], 0.f);
}

extern "C" void kernel_launch(void* const* d_in, const int* in_sizes, int n_in,
                              void* d_out, int out_size, void* d_ws, size_t ws_size,
                              hipStream_t stream) {
  const float* x0   = (const float*)d_in[0];
  const float* x1   = (const float*)d_in[1];
  const float* x2   = (const float*)d_in[2];
  const float* W    = (const float*)d_in[3];
  const float* bias = (const float*)d_in[4];
  float* out = (float*)d_out;

  ushort* U  = (ushort*)d_ws;                                   // 2048*2176*2 = 8,912,896 B
  ushort* Wt = (ushort*)((char*)d_ws + (size_t)8912896);        // 33*128*2176*2 = 18,382,848 B

  hipMemsetAsync(d_out, 0, (size_t)NROW * OO * sizeof(float), stream);
  prep_u_kernel<<<NROW, 256, 0, stream>>>(x1, x2, U);
  prep_wt_kernel<<<dim3(34, 33), 256, 0, stream>>>(W, Wt);
  gemm_kernel<<<528, 256, 0, stream>>>(U, Wt, x0, out);
  relu_kernel<<<(NROW * OO) / 256, 256, 0, stream>>>(out, bias);
}